// Round 9
// baseline (212.105 us; speedup 1.0000x reference)
//
#include <hip/hip_runtime.h>
#include <hip/hip_bf16.h>
#include <math.h>

// AttentionBlock: GN(8 groups) -> 1x1 conv q,k,v -> softmax(q^T k / 16) v -> 1x1 proj + residual
// b=4, c=256, hw=4096.
//
// R18 = R17 resubmit (container-level infra failure, no kernel verdict).
// R10-R16 eliminated every scheduling resource (interleave, L2, sync,
// pinned schedule, VALU, bank conflicts -> 0 with zero dur change). The
// invariant: ~96 cyc per MFMA instruction per wave, across all structures.
// Attack the instruction COUNT: mfma_scale_f32_32x32x64_f8f6f4 (fp8, unit
// scale 0x7F=1.0) does K=64/instr at 2.14x pipe rate. S = 4 instrs (K=256);
// O = 8 instrs per PAIR of kv-tiles (K=64 spans 2 tiles; hl=0 lanes hold
// tile-A P/V k-range, hl=1 tile-B -- the permlane32_swap pair-combine yields
// exactly this split free). 32 -> 8 MFMA/tile/wave. Plain LDS layouts (32B
// contiguous operands; conflicts proven non-binding by R16). V 4-deep for
// pair lifetime + 1-barrier skew safety. LDS 56KB, 2 blocks/CU, sync
// structure frozen from R13 (counted vmcnt + raw s_barrier).

#define CCH 256
#define NPIX 4096
#define NB 4
#define NG 8
#define EPS 1e-5f
#define NCHUNK 4

typedef __attribute__((ext_vector_type(8))) short short8;
typedef __attribute__((ext_vector_type(4))) short short4v;
typedef __attribute__((ext_vector_type(4))) float f32x4;
typedef __attribute__((ext_vector_type(16))) float f32x16;
typedef __attribute__((ext_vector_type(4))) int i32x4;
typedef __attribute__((ext_vector_type(8))) int i32x8;
typedef unsigned short ushort_t;
typedef unsigned char u8;

#define GLD16(g, l) __builtin_amdgcn_global_load_lds( \
    (const __attribute__((address_space(1))) unsigned int*)(g), \
    (__attribute__((address_space(3))) unsigned int*)(l), 16, 0, 0)

#define WAITV(n) asm volatile("s_waitcnt vmcnt(" #n ")" ::: "memory")

// K=64 fp8 MFMA with unit block-scales (e8m0 127 = 2^0 in every byte).
#define MXMFMA(A, B, C) __builtin_amdgcn_mfma_scale_f32_32x32x64_f8f6f4( \
    (A), (B), (C), 0, 0, 0, 0x7F7F7F7F, 0, 0x7F7F7F7F)

__device__ inline ushort_t f2bf(float x) {
    union { float f; unsigned u; } c; c.f = x;
    unsigned r = c.u + 0x7FFFu + ((c.u >> 16) & 1u);
    return (ushort_t)(r >> 16);
}
__device__ inline float bf2f(ushort_t h) {
    union { unsigned u; float f; } c; c.u = ((unsigned)h) << 16;
    return c.f;
}
__device__ inline u8 f2fp8(float x) {
    return (u8)(__builtin_amdgcn_cvt_pk_fp8_f32(x, x, 0, false) & 0xff);
}
__device__ inline i32x8 ld32(const u8* p) {
    i32x4 a = *(const i32x4*)p;
    i32x4 b = *(const i32x4*)(p + 16);
    i32x8 r;
    r[0] = a[0]; r[1] = a[1]; r[2] = a[2]; r[3] = a[3];
    r[4] = b[0]; r[5] = b[1]; r[6] = b[2]; r[7] = b[3];
    return r;
}

// ---------- GN stats stage1 (blocks 0..255) + weight f32->bf16 (256..511) ----------
__global__ __launch_bounds__(256) void gn1w(const float* __restrict__ x,
                                            const float* __restrict__ wq,
                                            const float* __restrict__ wk,
                                            const float* __restrict__ wv,
                                            const float* __restrict__ wp,
                                            float* __restrict__ part,
                                            ushort_t* __restrict__ wbf,
                                            ushort_t* __restrict__ wpbf) {
    int bid = blockIdx.x;
    int t = threadIdx.x;
    if (bid >= 256) {
        int widx = bid - 256;
        int wi = widx >> 6;
        const float* src = wi == 0 ? wq : wi == 1 ? wk : wi == 2 ? wv : wp;
        ushort_t* dst = wi == 3 ? wpbf : wbf + wi * 65536;
        int i = (widx & 63) * 1024 + t * 4;
        float4 v = *(const float4*)(src + i);
        short4v o;
        o[0] = (short)f2bf(v.x); o[1] = (short)f2bf(v.y);
        o[2] = (short)f2bf(v.z); o[3] = (short)f2bf(v.w);
        *(short4v*)(dst + i) = o;
        return;
    }
    int bg = bid >> 3;
    int slice = bid & 7;
    const float* base = x + (size_t)bg * 32 * NPIX + (size_t)slice * 16384;
    float s = 0.f, sq = 0.f;
    for (int i = t; i < 4096; i += 256) {
        float4 v = ((const float4*)base)[i];
        s  += v.x + v.y + v.z + v.w;
        sq += v.x*v.x + v.y*v.y + v.z*v.z + v.w*v.w;
    }
    for (int off = 32; off; off >>= 1) {
        s  += __shfl_down(s,  off);
        sq += __shfl_down(sq, off);
    }
    __shared__ float red[8];
    int wid = t >> 6;
    if ((t & 63) == 0) { red[wid*2] = s; red[wid*2+1] = sq; }
    __syncthreads();
    if (t == 0) {
        float ts = 0.f, tq = 0.f;
        for (int wv2 = 0; wv2 < 4; wv2++) { ts += red[wv2*2]; tq += red[wv2*2+1]; }
        part[bid*2] = ts; part[bid*2+1] = tq;
    }
}

// ---------- GN apply + transpose ----------
__global__ __launch_bounds__(256) void gn_transpose(const float* __restrict__ x,
                                                    const float* __restrict__ part,
                                                    const float* __restrict__ gamma,
                                                    const float* __restrict__ beta,
                                                    ushort_t* __restrict__ xnT) {
    __shared__ float T[64][69];
    __shared__ float gmean[2], grstd[2];
    int t = threadIdx.x;
    int nBase = blockIdx.x * 64;
    int cBase = blockIdx.y * 64;
    int b = blockIdx.z;
    if (t < 2) {
        int g = (cBase >> 5) + t;
        float s = 0.f, sq = 0.f;
        for (int i = 0; i < 8; i++) {
            s  += part[((b*NG + g)*8 + i)*2];
            sq += part[((b*NG + g)*8 + i)*2 + 1];
        }
        const float inv = 1.f / 131072.f;
        float mean = s * inv;
        float var = sq * inv - mean * mean;
        gmean[t] = mean;
        grstd[t] = rsqrtf(var + EPS);
    }
    __syncthreads();
    const float* xb = x + (size_t)b * CCH * NPIX;
    int n4  = (t & 15) * 4;
    int cc0 = (t >> 4) * 4;
    for (int i = 0; i < 4; i++) {
        int cc = cc0 + i;
        int c = cBase + cc;
        int gi = cc >> 5;
        float ga = gamma[c] * grstd[gi];
        float be = beta[c] - gmean[gi] * ga;
        float4 v = *(const float4*)&xb[(size_t)c * NPIX + nBase + n4];
        T[cc][n4+0] = v.x * ga + be;
        T[cc][n4+1] = v.y * ga + be;
        T[cc][n4+2] = v.z * ga + be;
        T[cc][n4+3] = v.w * ga + be;
    }
    __syncthreads();
    int nn  = t >> 2;
    int ci0 = (t & 3) * 16;
    short8 o0, o1;
    for (int j = 0; j < 8; j++) {
        o0[j] = (short)f2bf(T[ci0 + j][nn]);
        o1[j] = (short)f2bf(T[ci0 + 8 + j][nn]);
    }
    ushort_t* dst = xnT + ((size_t)b * NPIX + nBase + nn) * CCH + cBase + ci0;
    *(short8*)dst = o0;
    *((short8*)dst + 1) = o1;
}

// ---------- QKV: three 128x128-tile GEMMs; outputs q/k [n][c] fp8, v [b][c][n] fp8 ----------
__global__ __launch_bounds__(256, 2) void qkv3(const ushort_t* __restrict__ xnT,
                                               const ushort_t* __restrict__ wbf,
                                               const float* __restrict__ bq,
                                               const float* __restrict__ bk,
                                               const float* __restrict__ bv,
                                               u8* __restrict__ qT,
                                               u8* __restrict__ kT,
                                               u8* __restrict__ vv) {
    __shared__ __align__(16) ushort_t As[2][4096];
    __shared__ __align__(16) ushort_t Bs[2][4096];
    int t = threadIdx.x;
    int w = t >> 6, l = t & 63, quad = l >> 4, l16 = l & 15;
    int z = blockIdx.z;
    const ushort_t* A; const ushort_t* B; int mBase, nBase;
    if (z < 2) { A = xnT; B = wbf + z * 65536; mBase = blockIdx.x * 128; nBase = blockIdx.y * 128; }
    else       { A = wbf + 131072; B = xnT;    mBase = blockIdx.y * 128; nBase = blockIdx.x * 128; }
    int m0 = (w & 1) * 64, n0 = (w >> 1) * 64;

    const f32x4 fz = {0.f, 0.f, 0.f, 0.f};
    f32x4 acc[4][4];
    #pragma unroll
    for (int i = 0; i < 4; i++)
        #pragma unroll
        for (int j = 0; j < 4; j++) acc[i][j] = fz;

    int srow = t >> 2;
    int slc  = (t & 3) ^ ((t >> 2) & 3);
    int sldso = (t >> 6) * 512;

    #pragma unroll
    for (int j = 0; j < 2; j++) {
        int row = 64*j + srow;
        GLD16(A + (size_t)(mBase + row) * 256 + slc * 8, &As[0][j*2048 + sldso]);
        GLD16(B + (size_t)(nBase + row) * 256 + slc * 8, &Bs[0][j*2048 + sldso]);
    }
    int buf = 0;
    for (int kb = 0; kb < 8; kb++) {
        __syncthreads();
        if (kb < 7) {
            #pragma unroll
            for (int j = 0; j < 2; j++) {
                int row = 64*j + srow;
                GLD16(A + (size_t)(mBase + row) * 256 + (kb+1)*32 + slc * 8, &As[buf^1][j*2048 + sldso]);
                GLD16(B + (size_t)(nBase + row) * 256 + (kb+1)*32 + slc * 8, &Bs[buf^1][j*2048 + sldso]);
            }
        }
        short8 af[4], bfr[4];
        #pragma unroll
        for (int mb = 0; mb < 4; mb++)
            af[mb] = *(short8*)&As[buf][(m0 + mb*16 + l16)*32 + ((quad ^ (l16 & 3)) * 8)];
        #pragma unroll
        for (int nb = 0; nb < 4; nb++)
            bfr[nb] = *(short8*)&Bs[buf][(n0 + nb*16 + l16)*32 + ((quad ^ (l16 & 3)) * 8)];
        #pragma unroll
        for (int mb = 0; mb < 4; mb++)
            #pragma unroll
            for (int nb = 0; nb < 4; nb++)
                acc[mb][nb] = __builtin_amdgcn_mfma_f32_16x16x32_bf16(af[mb], bfr[nb], acc[mb][nb], 0, 0, 0);
        buf ^= 1;
    }
    if (z < 2) {
        const float* bias = z ? bk : bq;
        u8* C = z ? kT : qT;
        #pragma unroll
        for (int nb = 0; nb < 4; nb++) {
            int n = nBase + n0 + nb*16 + l16;
            float bb = bias[n];
            #pragma unroll
            for (int mb = 0; mb < 4; mb++)
                #pragma unroll
                for (int r = 0; r < 4; r++) {
                    int m = mBase + m0 + mb*16 + quad*4 + r;
                    C[(size_t)m * 256 + n] = f2fp8(acc[mb][nb][r] + bb);
                }
        }
    } else {
        #pragma unroll
        for (int mb = 0; mb < 4; mb++)
            #pragma unroll
            for (int r = 0; r < 4; r++) {
                int m = mBase + m0 + mb*16 + quad*4 + r;
                float bb = bv[m];
                #pragma unroll
                for (int nb = 0; nb < 4; nb++) {
                    int n = nBase + n0 + nb*16 + l16;
                    vv[((size_t)(n >> 12) * 256 + m) * 4096 + (n & 4095)] = f2fp8(acc[mb][nb][r] + bb);
                }
            }
    }
}

// ---------- Flash attention v17: K=64 MX MFMAs (8/tile/wave vs 32) ----------
// Grid 512 x 256 thr (4 waves, wave w: q rows qg*128 + w*32). flat%8 = XCD;
// each XCD owns 2 (chunk,b) combos. LDS: K 3x8KB + V 4x8KB = 56KB plain
// layouts -> 2 blocks/CU. Per-tile: issue K(tt+2),V(tt+1); vmcnt(4); raw
// s_barrier; at odd tt: O(pair tt-1,tt) 8 MX; S(tt+1) 4 MX; softmax(tt+1).
// O pair-combine: 4 permlane32_swap leave lane<32 with tile-A P-dwords and
// lane>=32 with tile-B -- exactly the x64 B-operand hl split. V A-operand:
// hl=0 lanes read V slot(even tile), hl=1 slot(odd tile).
__global__ __launch_bounds__(256, 2) void flash_attn(const u8* __restrict__ qT,
                                                     const u8* __restrict__ kT,
                                                     const u8* __restrict__ vv,
                                                     ushort_t* __restrict__ Op0,
                                                     ushort_t* __restrict__ Op1,
                                                     ushort_t* __restrict__ Op2,
                                                     ushort_t* __restrict__ Op3,
                                                     float* __restrict__ lsum) {
    __shared__ __align__(16) u8 KsAll[3 * 8192];
    __shared__ __align__(16) u8 VsAll[4 * 8192];
    int t = threadIdx.x;
    int w = t >> 6, l = t & 63;
    int l32 = l & 31, hl = l >> 5;
    int flat = blockIdx.x;
    int xcd = flat & 7;
    int ix = flat >> 3;                 // 0..63
    int combo = xcd + 8 * (ix >> 5);    // 0..15
    int qg = ix & 31;
    int chunk = combo & 3, b = combo >> 2;
    int qw = qg * 128 + w * 32;

    // Q B-frags: qf4[i] = Q[q=l32][c = i*64 + hl*32 .. +32)
    i32x8 qf4[4];
    {
        const u8* qrow = qT + ((size_t)b * NPIX + qw + l32) * 256 + hl * 32;
        #pragma unroll
        for (int i = 0; i < 4; i++) qf4[i] = ld32(qrow + i * 64);
    }

    f32x16 accO[8];
    #pragma unroll
    for (int i = 0; i < 8; i++)
        #pragma unroll
        for (int r = 0; r < 16; r++) accO[i][r] = 0.f;
    float lqa = 0.f;

    const u8* kbase = kT + (size_t)b * NPIX * 256;
    const u8* vbase = vv + (size_t)b * 256 * NPIX;

    const float SC = 0.0625f * 1.44269504089f;
    int mStart = chunk * (NPIX / NCHUNK);
    const int NT = (NPIX / NCHUNK) / 32;  // 32 kv-tiles per chunk

    // per-lane DMA source addresses (plain layouts); 2 GLD16 each for K, V
    const u8* kaddr[2];
    const u8* vaddr[2];
    #pragma unroll
    for (int j = 0; j < 2; j++) {
        int n = j * 256 + t;
        kaddr[j] = kbase + (size_t)(mStart + (n >> 4)) * 256 + (n & 15) * 16;
        vaddr[j] = vbase + (size_t)(n >> 1) * NPIX + mStart + (n & 1) * 16;
    }

#define KISSUE(tile, slot) { \
        unsigned koff_ = (unsigned)(tile) * 8192u; \
        _Pragma("unroll") \
        for (int j = 0; j < 2; j++) \
            GLD16(kaddr[j] + koff_, &KsAll[(slot)*8192 + (j*256 + t)*16]); }
#define VISSUE(tile, slot) { \
        unsigned voff_ = (unsigned)(tile) * 32u; \
        _Pragma("unroll") \
        for (int j = 0; j < 2; j++) \
            GLD16(vaddr[j] + voff_, &VsAll[(slot)*8192 + (j*256 + t)*16]); }

// S(tile in slot): 4 chained K=64 MFMAs. A = K rows (32B contiguous chans).
#define SCOMPUTE(slot) { \
        const u8* kb_ = &KsAll[(slot)*8192] + l32*256 + hl*32; \
        _Pragma("unroll") \
        for (int r = 0; r < 16; r++) sTa[r] = 0.f; \
        sTa = MXMFMA(ld32(kb_),       qf4[0], sTa); \
        sTa = MXMFMA(ld32(kb_ + 64),  qf4[1], sTa); \
        sTa = MXMFMA(ld32(kb_ + 128), qf4[2], sTa); \
        sTa = MXMFMA(ld32(kb_ + 192), qf4[3], sTa); }

// softmax -> 4 packed dwords (kv order: dst[a] = kv[8a+4hl .. +4))
#define SOFTMAX_PK(dst) { \
        float p_[16]; float q0_ = 0.f, q1_ = 0.f; \
        _Pragma("unroll") \
        for (int r = 0; r < 16; r++) { \
            float pe_ = exp2f(fmaf(sTa[r], SC, -5.0f)); \
            pe_ = fminf(pe_, 240.f); \
            p_[r] = pe_; \
            if (r & 1) q1_ += pe_; else q0_ += pe_; \
        } \
        lqa += q0_ + q1_; \
        dst[0] = (unsigned)__builtin_amdgcn_cvt_pk_fp8_f32(p_[2], p_[3], \
                 __builtin_amdgcn_cvt_pk_fp8_f32(p_[0], p_[1], 0, false), true); \
        dst[1] = (unsigned)__builtin_amdgcn_cvt_pk_fp8_f32(p_[6], p_[7], \
                 __builtin_amdgcn_cvt_pk_fp8_f32(p_[4], p_[5], 0, false), true); \
        dst[2] = (unsigned)__builtin_amdgcn_cvt_pk_fp8_f32(p_[10], p_[11], \
                 __builtin_amdgcn_cvt_pk_fp8_f32(p_[8], p_[9], 0, false), true); \
        dst[3] = (unsigned)__builtin_amdgcn_cvt_pk_fp8_f32(p_[14], p_[15], \
                 __builtin_amdgcn_cvt_pk_fp8_f32(p_[12], p_[13], 0, false), true); }

// O for pair (even tile slotE, odd tile slotO): combine pkA/pkB via 4 swaps
// (lane<32 ends with full tile-A kv bytes in order; lane>=32 tile-B), then
// 8 independent K=64 MFMAs. A = V rows; hl selects the tile's V slot.
#define OCOMPUTE(slotE, slotO) { \
        asm("v_permlane32_swap_b32 %0, %1" : "+v"(pkA[0]), "+v"(pkB[0])); \
        asm("v_permlane32_swap_b32 %0, %1" : "+v"(pkA[1]), "+v"(pkB[1])); \
        asm("v_permlane32_swap_b32 %0, %1" : "+v"(pkA[2]), "+v"(pkB[2])); \
        asm("v_permlane32_swap_b32 %0, %1" : "+v"(pkA[3]), "+v"(pkB[3])); \
        i32x8 pb; \
        pb[0] = (int)pkA[0]; pb[1] = (int)pkB[0]; \
        pb[2] = (int)pkA[1]; pb[3] = (int)pkB[1]; \
        pb[4] = (int)pkA[2]; pb[5] = (int)pkB[2]; \
        pb[6] = (int)pkA[3]; pb[7] = (int)pkB[3]; \
        const u8* vb_ = &VsAll[(hl ? (slotO) : (slotE)) * 8192] + l32*32; \
        _Pragma("unroll") \
        for (int cblk = 0; cblk < 8; cblk++) \
            accO[cblk] = MXMFMA(ld32(vb_ + cblk*1024), pb, accO[cblk]); }

    // prologue: K(0)->k0, V(0)->v0, K(1)->k1; drain to K(0)+V(0)
    KISSUE(0, 0);
    VISSUE(0, 0);
    KISSUE(1, 1);
    WAITV(2);
    __builtin_amdgcn_s_barrier();

    f32x16 sTa;
    unsigned pkA[4], pkB[4];
    SCOMPUTE(0);
    SOFTMAX_PK(pkA);   // tile 0 (even)

    int ks_r = 1, ks_w = 2;
    #pragma unroll 1
    for (int tt = 0; tt < NT - 2; ++tt) {
        KISSUE(tt + 2, ks_w);
        VISSUE(tt + 1, (tt + 1) & 3);
        WAITV(4);                      // own K(tt+1), V(tt) landed
        __builtin_amdgcn_s_barrier();
        __builtin_amdgcn_sched_barrier(0);
        __builtin_amdgcn_s_setprio(1);
        if (tt & 1) { OCOMPUTE((tt - 1) & 3, tt & 3); }
        SCOMPUTE(ks_r);
        __builtin_amdgcn_s_setprio(0);
        if (tt & 1) { SOFTMAX_PK(pkA); } else { SOFTMAX_PK(pkB); }
        ks_r = ks_r + 1; if (ks_r == 3) ks_r = 0;
        ks_w = ks_w + 1; if (ks_w == 3) ks_w = 0;
    }

    // tt = NT-2 = 30 (even): no more K to fetch; issue V(31); S(31)+softmax
    VISSUE(NT - 1, (NT - 1) & 3);
    WAITV(2);
    __builtin_amdgcn_s_barrier();
    __builtin_amdgcn_sched_barrier(0);
    __builtin_amdgcn_s_setprio(1);
    SCOMPUTE(ks_r);
    __builtin_amdgcn_s_setprio(0);
    SOFTMAX_PK(pkB);   // tile 31 (odd)

    // final pair (30, 31)
    WAITV(0);
    __builtin_amdgcn_s_barrier();
    __builtin_amdgcn_s_setprio(1);
    OCOMPUTE((NT - 2) & 3, (NT - 1) & 3);
    __builtin_amdgcn_s_setprio(0);

    // row-sums (lane + lane^32 hold complementary kv halves)
    {
        float v = lqa + __shfl_xor(lqa, 32);
        if (hl == 0)
            lsum[((size_t)chunk * NB + b) * NPIX + qw + l32] = v;
    }
    // unnormalized partial O (bf16): c = cblk*32 + a*8 + hl*4 + r, q = l32
    ushort_t* op = chunk == 0 ? Op0 : chunk == 1 ? Op1 : chunk == 2 ? Op2 : Op3;
    size_t rowb = ((size_t)b * NPIX + qw + l32) * CCH;
    #pragma unroll
    for (int cblk = 0; cblk < 8; cblk++)
        #pragma unroll
        for (int a = 0; a < 4; a++) {
            short4v o;
            #pragma unroll
            for (int r = 0; r < 4; r++) o[r] = (short)f2bf(accO[cblk][a*4 + r]);
            *(short4v*)&op[rowb + cblk*32 + a*8 + hl*4] = o;
        }
#undef KISSUE
#undef VISSUE
#undef SCOMPUTE
#undef SOFTMAX_PK
#undef OCOMPUTE
}

// ---------- Combine ----------
__global__ __launch_bounds__(256) void attn_combine(ushort_t* __restrict__ Op0,
                                                    const ushort_t* __restrict__ Op1,
                                                    const ushort_t* __restrict__ Op2,
                                                    const ushort_t* __restrict__ Op3,
                                                    const float* __restrict__ lsum) {
    const size_t BN = (size_t)NB * NPIX;
    size_t base = ((size_t)blockIdx.x * 256 + threadIdx.x) * 4;
    size_t bn = base >> 8;
    float li = 1.f / (lsum[bn] + lsum[BN + bn] + lsum[2*BN + bn] + lsum[3*BN + bn]);
    short4v a0 = *(short4v*)&Op0[base];
    short4v a1 = *(const short4v*)&Op1[base];
    short4v a2 = *(const short4v*)&Op2[base];
    short4v a3 = *(const short4v*)&Op3[base];
    short4v o;
    #pragma unroll
    for (int i = 0; i < 4; i++) {
        float v = (bf2f((ushort_t)a0[i]) + bf2f((ushort_t)a1[i]) +
                   bf2f((ushort_t)a2[i]) + bf2f((ushort_t)a3[i])) * li;
        o[i] = (short)f2bf(v);
    }
    *(short4v*)&Op0[base] = o;
}

// ---------- Projection GEMM + bias + residual (f32 out) ----------
__global__ __launch_bounds__(256, 2) void projk(const ushort_t* __restrict__ wpbf,
                                                const ushort_t* __restrict__ aoT,
                                                const float* __restrict__ bp,
                                                const float* __restrict__ x,
                                                float* __restrict__ out) {
    __shared__ __align__(16) ushort_t As[2][4096];
    __shared__ __align__(16) ushort_t Bs[2][4096];
    int t = threadIdx.x;
    int w = t >> 6, l = t & 63, quad = l >> 4, l16 = l & 15;
    int mBase = blockIdx.y * 128, nBase = blockIdx.x * 128;
    int m0 = (w & 1) * 64, n0 = (w >> 1) * 64;

    const f32x4 fz = {0.f, 0.f, 0.f, 0.f};
    f32x4 acc[4][4];
    #pragma unroll
    for (int i = 0; i < 4; i++)
        #pragma unroll
        for (int j = 0; j < 4; j++) acc[i][j] = fz;

    int srow = t >> 2;
    int slc  = (t & 3) ^ ((t >> 2) & 3);
    int sldso = (t >> 6) * 512;

    #pragma unroll
    for (int j = 0; j < 2; j++) {
        int row = 64*j + srow;
        GLD16(wpbf + (size_t)(mBase + row) * 256 + slc * 8, &As[0][j*2048 + sldso]);
        GLD16(aoT  + (size_t)(nBase + row) * 256 + slc * 8, &Bs[0][j*2048 + sldso]);
    }
    int buf = 0;
    for (int kb = 0; kb < 8; kb++) {
        __syncthreads();
        if (kb < 7) {
            #pragma unroll
            for (int j = 0; j < 2; j++) {
                int row = 64*j + srow;
                GLD16(wpbf + (size_t)(mBase + row) * 256 + (kb+1)*32 + slc * 8, &As[buf^1][j*2048 + sldso]);
                GLD16(aoT  + (size_t)(nBase + row) * 256 + (kb+1)*32 + slc * 8, &Bs[buf^1][j*2048 + sldso]);
            }
        }
        short8 af[4], bfr[4];
        #pragma unroll
        for (int mb = 0; mb < 4; mb++)
            af[mb] = *(short8*)&As[buf][(m0 + mb*16 + l16)*32 + ((quad ^ (l16 & 3)) * 8)];
        #pragma unroll
        for (int nb = 0; nb < 4; nb++)
            bfr[nb] = *(short8*)&Bs[buf][(n0 + nb*16 + l16)*32 + ((quad ^ (l16 & 3)) * 8)];
        #pragma unroll
        for (int mb = 0; mb < 4; mb++)
            #pragma unroll
            for (int nb = 0; nb < 4; nb++)
                acc[mb][nb] = __builtin_amdgcn_mfma_f32_16x16x32_bf16(af[mb], bfr[nb], acc[mb][nb], 0, 0, 0);
        buf ^= 1;
    }
    #pragma unroll
    for (int mb = 0; mb < 4; mb++)
        #pragma unroll
        for (int r = 0; r < 4; r++) {
            int m = mBase + m0 + mb*16 + quad*4 + r;
            float bb = bp[m];
            #pragma unroll
            for (int nb = 0; nb < 4; nb++) {
                int n = nBase + n0 + nb*16 + l16;
                size_t idx = ((size_t)(n >> 12) * 256 + m) * 4096 + (n & 4095);
                out[idx] = acc[mb][nb][r] + bb + x[idx];
            }
        }
}

extern "C" void kernel_launch(void* const* d_in, const int* in_sizes, int n_in,
                              void* d_out, int out_size, void* d_ws, size_t ws_size,
                              hipStream_t stream) {
    const float* x     = (const float*)d_in[0];
    const float* gamma = (const float*)d_in[1];
    const float* beta  = (const float*)d_in[2];
    const float* wq    = (const float*)d_in[3];
    const float* bq    = (const float*)d_in[4];
    const float* wk    = (const float*)d_in[5];
    const float* bk    = (const float*)d_in[6];
    const float* wv    = (const float*)d_in[7];
    const float* bv    = (const float*)d_in[8];
    const float* wp    = (const float*)d_in[9];
    const float* bp    = (const float*)d_in[10];
    float* out = (float*)d_out;

    const size_t SZ = (size_t)NB * NPIX * CCH;
    float* part  = (float*)d_ws;
    float* lsum  = part + 512;
    ushort_t* wpbf = (ushort_t*)(lsum + (size_t)NCHUNK * NB * NPIX);
    ushort_t* slot0 = wpbf + 65536;
    ushort_t* Op3 = slot0;
    u8* qT8 = (u8*)(slot0 + SZ);           // fp8, 4 MB used of 8 MB slot
    u8* kT8 = (u8*)(slot0 + 2*SZ);
    u8* vv8 = (u8*)(slot0 + 3*SZ);
    ushort_t* aoT = slot0 + 4*SZ;          // Op0, combined in-place -> aoT
    ushort_t* xnT = (ushort_t*)d_out;      // [0,8M): xnT, later Op1
    ushort_t* Op1 = (ushort_t*)d_out;
    ushort_t* Op2 = (ushort_t*)d_out + SZ; // [8M,16M): wbf (pre-qkv), later Op2
    ushort_t* wbf = (ushort_t*)d_out + SZ;

    gn1w<<<512, 256, 0, stream>>>(x, wq, wk, wv, wp, part, wbf, wpbf);
    gn_transpose<<<dim3(64, 4, 4), 256, 0, stream>>>(x, part, gamma, beta, xnT);
    qkv3<<<dim3(128, 2, 3), 256, 0, stream>>>(xnT, wbf, bq, bk, bv, qT8, kT8, vv8);
    flash_attn<<<dim3(512), 256, 0, stream>>>(qT8, kT8, vv8, aoT, Op1, Op2, Op3, lsum);
    attn_combine<<<(int)(SZ / 1024), 256, 0, stream>>>(aoT, Op1, Op2, Op3, lsum);
    projk<<<dim3(128, 2), 256, 0, stream>>>(wpbf, aoT, bp, x, out);
}

// Round 11
// 200.189 us; speedup vs baseline: 1.0595x; 1.0595x over previous
//
#include <hip/hip_runtime.h>
#include <hip/hip_bf16.h>
#include <math.h>

// AttentionBlock: GN(8 groups) -> 1x1 conv q,k,v -> softmax(q^T k / 16) v -> 1x1 proj + residual
// b=4, c=256, hw=4096.
//
// R20 = R19 with the prefetch race FIXED. R19 issued K(a+4)/V(a+3) BEFORE
// the phase barrier -> zero-barrier separation from phase j-1's laggard
// readers of those slots (R13-R16's 3-deep scheme had 2-barrier separation;
// the 2-tile variant lost it). Fix: per phase, WAITV(0) (drains loads issued
// a FULL PHASE earlier -> effectively free) -> raw s_barrier -> THEN issue
// the 8 prefetch loads -> BURST+softmax x2. Slot written in phase j was
// last read in phase j-1, and the write now sits after phase j's barrier:
// safe for <=1-phase skew. Hypothesis unchanged: halve the per-tile
// rendezvous count (17 barriers vs R16's 33) to attack the ~60% idle.

#define CCH 256
#define NPIX 4096
#define NB 4
#define NG 8
#define EPS 1e-5f
#define NCHUNK 4

typedef __attribute__((ext_vector_type(8))) short short8;
typedef __attribute__((ext_vector_type(4))) short short4v;
typedef __attribute__((ext_vector_type(4))) float f32x4;
typedef __attribute__((ext_vector_type(16))) float f32x16;
typedef unsigned short ushort_t;
typedef unsigned char u8;

#define GLD16(g, l) __builtin_amdgcn_global_load_lds( \
    (const __attribute__((address_space(1))) unsigned int*)(g), \
    (__attribute__((address_space(3))) unsigned int*)(l), 16, 0, 0)

#define WAITV(n) asm volatile("s_waitcnt vmcnt(" #n ")" ::: "memory")

__device__ inline ushort_t f2bf(float x) {
    union { float f; unsigned u; } c; c.f = x;
    unsigned r = c.u + 0x7FFFu + ((c.u >> 16) & 1u);
    return (ushort_t)(r >> 16);
}
__device__ inline float bf2f(ushort_t h) {
    union { unsigned u; float f; } c; c.u = ((unsigned)h) << 16;
    return c.f;
}
__device__ inline u8 f2fp8(float x) {
    return (u8)(__builtin_amdgcn_cvt_pk_fp8_f32(x, x, 0, false) & 0xff);
}
__device__ inline long mk64(unsigned lo, unsigned hi) {
    return (long)(((unsigned long long)hi << 32) | lo);
}

// ---------- GN stats stage1 (blocks 0..255) + weight f32->bf16 (256..511) ----------
__global__ __launch_bounds__(256) void gn1w(const float* __restrict__ x,
                                            const float* __restrict__ wq,
                                            const float* __restrict__ wk,
                                            const float* __restrict__ wv,
                                            const float* __restrict__ wp,
                                            float* __restrict__ part,
                                            ushort_t* __restrict__ wbf,
                                            ushort_t* __restrict__ wpbf) {
    int bid = blockIdx.x;
    int t = threadIdx.x;
    if (bid >= 256) {
        int widx = bid - 256;
        int wi = widx >> 6;
        const float* src = wi == 0 ? wq : wi == 1 ? wk : wi == 2 ? wv : wp;
        ushort_t* dst = wi == 3 ? wpbf : wbf + wi * 65536;
        int i = (widx & 63) * 1024 + t * 4;
        float4 v = *(const float4*)(src + i);
        short4v o;
        o[0] = (short)f2bf(v.x); o[1] = (short)f2bf(v.y);
        o[2] = (short)f2bf(v.z); o[3] = (short)f2bf(v.w);
        *(short4v*)(dst + i) = o;
        return;
    }
    int bg = bid >> 3;
    int slice = bid & 7;
    const float* base = x + (size_t)bg * 32 * NPIX + (size_t)slice * 16384;
    float s = 0.f, sq = 0.f;
    for (int i = t; i < 4096; i += 256) {
        float4 v = ((const float4*)base)[i];
        s  += v.x + v.y + v.z + v.w;
        sq += v.x*v.x + v.y*v.y + v.z*v.z + v.w*v.w;
    }
    for (int off = 32; off; off >>= 1) {
        s  += __shfl_down(s,  off);
        sq += __shfl_down(sq, off);
    }
    __shared__ float red[8];
    int wid = t >> 6;
    if ((t & 63) == 0) { red[wid*2] = s; red[wid*2+1] = sq; }
    __syncthreads();
    if (t == 0) {
        float ts = 0.f, tq = 0.f;
        for (int wv2 = 0; wv2 < 4; wv2++) { ts += red[wv2*2]; tq += red[wv2*2+1]; }
        part[bid*2] = ts; part[bid*2+1] = tq;
    }
}

// ---------- GN apply + transpose ----------
__global__ __launch_bounds__(256) void gn_transpose(const float* __restrict__ x,
                                                    const float* __restrict__ part,
                                                    const float* __restrict__ gamma,
                                                    const float* __restrict__ beta,
                                                    ushort_t* __restrict__ xnT) {
    __shared__ float T[64][69];
    __shared__ float gmean[2], grstd[2];
    int t = threadIdx.x;
    int nBase = blockIdx.x * 64;
    int cBase = blockIdx.y * 64;
    int b = blockIdx.z;
    if (t < 2) {
        int g = (cBase >> 5) + t;
        float s = 0.f, sq = 0.f;
        for (int i = 0; i < 8; i++) {
            s  += part[((b*NG + g)*8 + i)*2];
            sq += part[((b*NG + g)*8 + i)*2 + 1];
        }
        const float inv = 1.f / 131072.f;
        float mean = s * inv;
        float var = sq * inv - mean * mean;
        gmean[t] = mean;
        grstd[t] = rsqrtf(var + EPS);
    }
    __syncthreads();
    const float* xb = x + (size_t)b * CCH * NPIX;
    int n4  = (t & 15) * 4;
    int cc0 = (t >> 4) * 4;
    for (int i = 0; i < 4; i++) {
        int cc = cc0 + i;
        int c = cBase + cc;
        int gi = cc >> 5;
        float ga = gamma[c] * grstd[gi];
        float be = beta[c] - gmean[gi] * ga;
        float4 v = *(const float4*)&xb[(size_t)c * NPIX + nBase + n4];
        T[cc][n4+0] = v.x * ga + be;
        T[cc][n4+1] = v.y * ga + be;
        T[cc][n4+2] = v.z * ga + be;
        T[cc][n4+3] = v.w * ga + be;
    }
    __syncthreads();
    int nn  = t >> 2;
    int ci0 = (t & 3) * 16;
    short8 o0, o1;
    for (int j = 0; j < 8; j++) {
        o0[j] = (short)f2bf(T[ci0 + j][nn]);
        o1[j] = (short)f2bf(T[ci0 + 8 + j][nn]);
    }
    ushort_t* dst = xnT + ((size_t)b * NPIX + nBase + nn) * CCH + cBase + ci0;
    *(short8*)dst = o0;
    *((short8*)dst + 1) = o1;
}

// ---------- QKV: three 128x128-tile GEMMs; outputs q/k [n][c] fp8, v [b][c][n] fp8 ----------
// k and v stores swap the 8B halves of each 16B slot when (m>>3)&1 (m = kv
// row for k, channel for v) so flash's ds_read banks spread 2-way (R16).
__global__ __launch_bounds__(256, 2) void qkv3(const ushort_t* __restrict__ xnT,
                                               const ushort_t* __restrict__ wbf,
                                               const float* __restrict__ bq,
                                               const float* __restrict__ bk,
                                               const float* __restrict__ bv,
                                               u8* __restrict__ qT,
                                               u8* __restrict__ kT,
                                               u8* __restrict__ vv) {
    __shared__ __align__(16) ushort_t As[2][4096];
    __shared__ __align__(16) ushort_t Bs[2][4096];
    int t = threadIdx.x;
    int w = t >> 6, l = t & 63, quad = l >> 4, l16 = l & 15;
    int z = blockIdx.z;
    const ushort_t* A; const ushort_t* B; int mBase, nBase;
    if (z < 2) { A = xnT; B = wbf + z * 65536; mBase = blockIdx.x * 128; nBase = blockIdx.y * 128; }
    else       { A = wbf + 131072; B = xnT;    mBase = blockIdx.y * 128; nBase = blockIdx.x * 128; }
    int m0 = (w & 1) * 64, n0 = (w >> 1) * 64;

    const f32x4 fz = {0.f, 0.f, 0.f, 0.f};
    f32x4 acc[4][4];
    #pragma unroll
    for (int i = 0; i < 4; i++)
        #pragma unroll
        for (int j = 0; j < 4; j++) acc[i][j] = fz;

    int srow = t >> 2;
    int slc  = (t & 3) ^ ((t >> 2) & 3);
    int sldso = (t >> 6) * 512;

    #pragma unroll
    for (int j = 0; j < 2; j++) {
        int row = 64*j + srow;
        GLD16(A + (size_t)(mBase + row) * 256 + slc * 8, &As[0][j*2048 + sldso]);
        GLD16(B + (size_t)(nBase + row) * 256 + slc * 8, &Bs[0][j*2048 + sldso]);
    }
    int buf = 0;
    for (int kb = 0; kb < 8; kb++) {
        __syncthreads();
        if (kb < 7) {
            #pragma unroll
            for (int j = 0; j < 2; j++) {
                int row = 64*j + srow;
                GLD16(A + (size_t)(mBase + row) * 256 + (kb+1)*32 + slc * 8, &As[buf^1][j*2048 + sldso]);
                GLD16(B + (size_t)(nBase + row) * 256 + (kb+1)*32 + slc * 8, &Bs[buf^1][j*2048 + sldso]);
            }
        }
        short8 af[4], bfr[4];
        #pragma unroll
        for (int mb = 0; mb < 4; mb++)
            af[mb] = *(short8*)&As[buf][(m0 + mb*16 + l16)*32 + ((quad ^ (l16 & 3)) * 8)];
        #pragma unroll
        for (int nb = 0; nb < 4; nb++)
            bfr[nb] = *(short8*)&Bs[buf][(n0 + nb*16 + l16)*32 + ((quad ^ (l16 & 3)) * 8)];
        #pragma unroll
        for (int mb = 0; mb < 4; mb++)
            #pragma unroll
            for (int nb = 0; nb < 4; nb++)
                acc[mb][nb] = __builtin_amdgcn_mfma_f32_16x16x32_bf16(af[mb], bfr[nb], acc[mb][nb], 0, 0, 0);
        buf ^= 1;
    }
    if (z < 2) {
        const float* bias = z ? bk : bq;
        u8* C = z ? kT : qT;
        #pragma unroll
        for (int nb = 0; nb < 4; nb++) {
            int n = nBase + n0 + nb*16 + l16;
            float bb = bias[n];
            #pragma unroll
            for (int mb = 0; mb < 4; mb++)
                #pragma unroll
                for (int r = 0; r < 4; r++) {
                    int m = mBase + m0 + mb*16 + quad*4 + r;
                    // k rows with (m>>3)&1: swap 8B halves within 16B slots
                    int nc = z ? (n ^ (((m >> 3) & 1) << 3)) : n;
                    C[(size_t)m * 256 + nc] = f2fp8(acc[mb][nb][r] + bb);
                }
        }
    } else {
        #pragma unroll
        for (int mb = 0; mb < 4; mb++)
            #pragma unroll
            for (int r = 0; r < 4; r++) {
                int m = mBase + m0 + mb*16 + quad*4 + r;
                float bb = bv[m];
                int sw8 = ((m >> 3) & 1) << 3;
                #pragma unroll
                for (int nb = 0; nb < 4; nb++) {
                    int n = nBase + n0 + nb*16 + l16;
                    vv[((size_t)(n >> 12) * 256 + m) * 4096 + ((n & 4095) ^ sw8)] = f2fp8(acc[mb][nb][r] + bb);
                }
            }
    }
}

// ---------- Flash attention v20: two tiles per barrier phase, race-free protocol ----------
// Grid 512 x 256 thr (4 waves, wave w: q rows qg*128 + w*32). flat%8 = XCD;
// each XCD owns 2 (chunk,b) combos (1MB K/V, L2-resident). LDS: K 4x8KB +
// V 4x8KB = 64KB (slot = tile&3). Phase j (tiles a=2j, a+1):
//   WAITV(0)  [drains the 8 loads issued in phase j-1 -- a full phase ago]
//   raw s_barrier
//   issue K(a+3),K(a+4),V(a+2),V(a+3)   [8 loads, AFTER the barrier]
//   BURST(S(a+1),O(a)); softmax; BURST(S(a+2),O(a+1)); softmax.
// Slot written in phase j was last read in phase j-1 and the write-issue is
// behind phase j's barrier -> safe for <=1-phase wave skew. 17 barriers vs
// R16's 33. Reads use half (hl ^ ((l32>>3)&1)) matching qkv3's stored
// half-swap -> 2-way banks (conflicts ~0, proven R16).
__global__ __launch_bounds__(256, 2) void flash_attn(const u8* __restrict__ qT,
                                                     const u8* __restrict__ kT,
                                                     const u8* __restrict__ vv,
                                                     ushort_t* __restrict__ Op0,
                                                     ushort_t* __restrict__ Op1,
                                                     ushort_t* __restrict__ Op2,
                                                     ushort_t* __restrict__ Op3,
                                                     float* __restrict__ lsum) {
    __shared__ __align__(16) u8 KsAll[4 * 8192];
    __shared__ __align__(16) u8 VsAll[4 * 8192];
    int t = threadIdx.x;
    int w = t >> 6, l = t & 63;
    int l32 = l & 31, hl = l >> 5;
    // XCD-bijective swizzle: each XCD gets 2 full (chunk,b) combos
    int flat = blockIdx.x;
    int xcd = flat & 7;
    int ix = flat >> 3;                 // 0..63
    int combo = xcd + 8 * (ix >> 5);    // 0..15
    int qg = ix & 31;
    int chunk = combo & 3, b = combo >> 2;
    int qw = qg * 128 + w * 32;

    // Q B-frags (fp8): qf[cb] = Q[q=l32][c = cb*16 + hl*8 + j]
    long qf[16];
    {
        const u8* qrow = qT + ((size_t)b * NPIX + qw + l32) * 256 + hl * 8;
        #pragma unroll
        for (int cb = 0; cb < 16; cb++) qf[cb] = *(const long*)(qrow + cb * 16);
    }

    f32x16 accO[8];
    #pragma unroll
    for (int i = 0; i < 8; i++)
        #pragma unroll
        for (int r = 0; r < 16; r++) accO[i][r] = 0.f;
    float lqa = 0.f;

    const u8* kbase = kT + (size_t)b * NPIX * 256;
    const u8* vbase = vv + (size_t)b * 256 * NPIX;

    const float SC = 0.0625f * 1.44269504089f;
    int mStart = chunk * (NPIX / NCHUNK);

    // per-lane DMA source addresses (mStart folded in); 2 GLD16 each for K, V
    const u8* kaddr[2];
    const u8* vaddr[2];
    #pragma unroll
    for (int j = 0; j < 2; j++) {
        int n = j * 256 + t;
        int kkv = n >> 4, kcb = (n & 15) ^ (kkv & 7);
        int vc = n >> 1,  vsw = (n & 1) ^ ((vc >> 2) & 1);
        kaddr[j] = kbase + (size_t)(mStart + kkv) * 256 + kcb * 16;
        vaddr[j] = vbase + (size_t)vc * NPIX + mStart + vsw * 16;
    }

    // tile-invariant LDS read offsets (start at slot 0); half-swap bit g
    int g8 = (hl ^ ((l32 >> 3) & 1)) * 8;
    int kO[8];
    #pragma unroll
    for (int c = 0; c < 8; c++) kO[c] = l32 * 256 + ((c ^ (l32 & 7)) * 16) + g8;
    int sw0 = (l32 >> 2) & 1;
    int vO0 = l32 * 32 + (sw0 ^ 0) * 16 + g8;
    int vO1 = l32 * 32 + (sw0 ^ 1) * 16 + g8;

#define LDK(c) (*(const long*)&KsAll[kO[(c) & 7] + (((c) & 8) << 4)])
#define LDV0(m) (*(const long*)&VsAll[vO0 + (m) * 1024])
#define LDV1(m) (*(const long*)&VsAll[vO1 + (m) * 1024])

#define KISSUE(tile, slot) { \
        unsigned koff_ = (unsigned)(tile) * 8192u; \
        _Pragma("unroll") \
        for (int j = 0; j < 2; j++) \
            GLD16(kaddr[j] + koff_, &KsAll[(slot)*8192 + (j*256 + t)*16]); }
#define VISSUE(tile, slot) { \
        unsigned voff_ = (unsigned)(tile) * 32u; \
        _Pragma("unroll") \
        for (int j = 0; j < 2; j++) \
            GLD16(vaddr[j] + voff_, &VsAll[(slot)*8192 + (j*256 + t)*16]); }

#define SOFTMAX_PACK() { \
        float p_[16]; float q0_ = 0.f, q1_ = 0.f; \
        _Pragma("unroll") \
        for (int r = 0; r < 16; r++) { \
            float pe_ = exp2f(fmaf(sTa[r], SC, -5.0f)); \
            pe_ = fminf(pe_, 240.f); \
            p_[r] = pe_; \
            if (r & 1) q1_ += pe_; else q0_ += pe_; \
        } \
        lqa += q0_ + q1_; \
        unsigned pk0_ = (unsigned)__builtin_amdgcn_cvt_pk_fp8_f32(p_[2], p_[3], \
                        __builtin_amdgcn_cvt_pk_fp8_f32(p_[0], p_[1], 0, false), true); \
        unsigned pk1_ = (unsigned)__builtin_amdgcn_cvt_pk_fp8_f32(p_[6], p_[7], \
                        __builtin_amdgcn_cvt_pk_fp8_f32(p_[4], p_[5], 0, false), true); \
        unsigned pk2_ = (unsigned)__builtin_amdgcn_cvt_pk_fp8_f32(p_[10], p_[11], \
                        __builtin_amdgcn_cvt_pk_fp8_f32(p_[8], p_[9], 0, false), true); \
        unsigned pk3_ = (unsigned)__builtin_amdgcn_cvt_pk_fp8_f32(p_[14], p_[15], \
                        __builtin_amdgcn_cvt_pk_fp8_f32(p_[12], p_[13], 0, false), true); \
        asm("v_permlane32_swap_b32 %0, %1" : "+v"(pk0_), "+v"(pk1_)); \
        asm("v_permlane32_swap_b32 %0, %1" : "+v"(pk2_), "+v"(pk3_)); \
        B0 = mk64(pk0_, pk1_); \
        B1 = mk64(pk2_, pk3_); }

// Burst: single 16-deep S chain (next tile, K @ kO's current slot)
// interleaved with 16 O MFMAs (current tile, V @ vO's current slot).
#define BURST() { \
        _Pragma("unroll") \
        for (int r = 0; r < 16; r++) sTa[r] = 0.f; \
        _Pragma("unroll") \
        for (int m = 0; m < 8; m++) { \
            sTa = __builtin_amdgcn_mfma_f32_32x32x16_fp8_fp8(LDK(2*m), qf[2*m], sTa, 0, 0, 0); \
            accO[m] = __builtin_amdgcn_mfma_f32_32x32x16_fp8_fp8(LDV0(m), B0, accO[m], 0, 0, 0); \
            sTa = __builtin_amdgcn_mfma_f32_32x32x16_fp8_fp8(LDK(2*m+1), qf[2*m+1], sTa, 0, 0, 0); \
            accO[m] = __builtin_amdgcn_mfma_f32_32x32x16_fp8_fp8(LDV1(m), B1, accO[m], 0, 0, 0); \
        } }

// rotate kO / vO to the next slot
#define ADV_K() { int d_ = (ksl == 3) ? -24576 : 8192; \
        _Pragma("unroll") \
        for (int c = 0; c < 8; c++) kO[c] += d_; \
        ksl = (ksl + 1) & 3; }
#define ADV_V() { int d_ = (vsl == 3) ? -24576 : 8192; \
        vO0 += d_; vO1 += d_; vsl = (vsl + 1) & 3; }

    // prologue: K0..K2 -> slots 0..2, V0,V1 -> slots 0,1 (10 loads), full drain
    KISSUE(0, 0);
    KISSUE(1, 1);
    KISSUE(2, 2);
    VISSUE(0, 0);
    VISSUE(1, 1);
    WAITV(0);
    __builtin_amdgcn_s_barrier();

    // S(0) = K(0)·Q  (kO at slot 0)
    f32x16 sTa;
    #pragma unroll
    for (int r = 0; r < 16; r++) sTa[r] = 0.f;
    #pragma unroll
    for (int cb = 0; cb < 16; cb++)
        sTa = __builtin_amdgcn_mfma_f32_32x32x16_fp8_fp8(LDK(cb), qf[cb], sTa, 0, 0, 0);
    long B0, B1;
    SOFTMAX_PACK();                  // B(0)

    int ksl = 0, vsl = 0;
    ADV_K();                         // kO -> slot 1 (for S(1))

    // 14 full phases: tiles (2j, 2j+1), j = 0..13
    #pragma unroll 1
    for (int j = 0; j < 14; ++j) {
        int a = 2 * j;
        WAITV(0);                    // drain loads issued in phase j-1 (full phase ago)
        __builtin_amdgcn_s_barrier();
        __builtin_amdgcn_sched_barrier(0);
        // prefetch AFTER the barrier: slots being written were last read in
        // phase j-1, which all waves left at the barrier above.
        KISSUE(a + 3, (a + 3) & 3);
        KISSUE(a + 4, (a + 4) & 3);
        VISSUE(a + 2, (a + 2) & 3);
        VISSUE(a + 3, (a + 3) & 3);
        __builtin_amdgcn_s_setprio(1);
        BURST();                     // S(a+1), O(a)
        __builtin_amdgcn_s_setprio(0);
        SOFTMAX_PACK();              // B(a+1)
        ADV_K(); ADV_V();
        __builtin_amdgcn_s_setprio(1);
        BURST();                     // S(a+2), O(a+1)
        __builtin_amdgcn_s_setprio(0);
        SOFTMAX_PACK();              // B(a+2)
        ADV_K(); ADV_V();
    }

    // phase 14: tiles 28,29; prefetch K(31),V(30),V(31) (6 loads)
    WAITV(0);
    __builtin_amdgcn_s_barrier();
    __builtin_amdgcn_sched_barrier(0);
    KISSUE(31, 31 & 3);
    VISSUE(30, 30 & 3);
    VISSUE(31, 31 & 3);
    __builtin_amdgcn_s_setprio(1);
    BURST();                         // S(29), O(28)
    __builtin_amdgcn_s_setprio(0);
    SOFTMAX_PACK();                  // B(29)
    ADV_K(); ADV_V();
    __builtin_amdgcn_s_setprio(1);
    BURST();                         // S(30), O(29)
    __builtin_amdgcn_s_setprio(0);
    SOFTMAX_PACK();                  // B(30)
    ADV_K(); ADV_V();

    // final phase: tiles 30,31
    WAITV(0);
    __builtin_amdgcn_s_barrier();
    __builtin_amdgcn_sched_barrier(0);
    __builtin_amdgcn_s_setprio(1);
    BURST();                         // S(31), O(30)
    __builtin_amdgcn_s_setprio(0);
    SOFTMAX_PACK();                  // B(31)
    ADV_V();
    __builtin_amdgcn_s_setprio(1);
    #pragma unroll
    for (int m = 0; m < 8; m++) {    // O(31) only
        accO[m] = __builtin_amdgcn_mfma_f32_32x32x16_fp8_fp8(LDV0(m), B0, accO[m], 0, 0, 0);
        accO[m] = __builtin_amdgcn_mfma_f32_32x32x16_fp8_fp8(LDV1(m), B1, accO[m], 0, 0, 0);
    }
    __builtin_amdgcn_s_setprio(0);

    // row-sums (lane + lane^32 hold complementary kv halves)
    {
        float v = lqa + __shfl_xor(lqa, 32);
        if (hl == 0)
            lsum[((size_t)chunk * NB + b) * NPIX + qw + l32] = v;
    }
    // unnormalized partial O (bf16): c = cblk*32 + a*8 + hl*4 + r, q = l32
    ushort_t* op = chunk == 0 ? Op0 : chunk == 1 ? Op1 : chunk == 2 ? Op2 : Op3;
    size_t rowb = ((size_t)b * NPIX + qw + l32) * CCH;
    #pragma unroll
    for (int cblk = 0; cblk < 8; cblk++)
        #pragma unroll
        for (int a = 0; a < 4; a++) {
            short4v o;
            #pragma unroll
            for (int r = 0; r < 4; r++) o[r] = (short)f2bf(accO[cblk][a*4 + r]);
            *(short4v*)&op[rowb + cblk*32 + a*8 + hl*4] = o;
        }
#undef LDK
#undef LDV0
#undef LDV1
#undef KISSUE
#undef VISSUE
#undef SOFTMAX_PACK
#undef BURST
#undef ADV_K
#undef ADV_V
}

// ---------- Combine ----------
__global__ __launch_bounds__(256) void attn_combine(ushort_t* __restrict__ Op0,
                                                    const ushort_t* __restrict__ Op1,
                                                    const ushort_t* __restrict__ Op2,
                                                    const ushort_t* __restrict__ Op3,
                                                    const float* __restrict__ lsum) {
    const size_t BN = (size_t)NB * NPIX;
    size_t base = ((size_t)blockIdx.x * 256 + threadIdx.x) * 4;
    size_t bn = base >> 8;
    float li = 1.f / (lsum[bn] + lsum[BN + bn] + lsum[2*BN + bn] + lsum[3*BN + bn]);
    short4v a0 = *(short4v*)&Op0[base];
    short4v a1 = *(const short4v*)&Op1[base];
    short4v a2 = *(const short4v*)&Op2[base];
    short4v a3 = *(const short4v*)&Op3[base];
    short4v o;
    #pragma unroll
    for (int i = 0; i < 4; i++) {
        float v = (bf2f((ushort_t)a0[i]) + bf2f((ushort_t)a1[i]) +
                   bf2f((ushort_t)a2[i]) + bf2f((ushort_t)a3[i])) * li;
        o[i] = (short)f2bf(v);
    }
    *(short4v*)&Op0[base] = o;
}

// ---------- Projection GEMM + bias + residual (f32 out) ----------
__global__ __launch_bounds__(256, 2) void projk(const ushort_t* __restrict__ wpbf,
                                                const ushort_t* __restrict__ aoT,
                                                const float* __restrict__ bp,
                                                const float* __restrict__ x,
                                                float* __restrict__ out) {
    __shared__ __align__(16) ushort_t As[2][4096];
    __shared__ __align__(16) ushort_t Bs[2][4096];
    int t = threadIdx.x;
    int w = t >> 6, l = t & 63, quad = l >> 4, l16 = l & 15;
    int mBase = blockIdx.y * 128, nBase = blockIdx.x * 128;
    int m0 = (w & 1) * 64, n0 = (w >> 1) * 64;

    const f32x4 fz = {0.f, 0.f, 0.f, 0.f};
    f32x4 acc[4][4];
    #pragma unroll
    for (int i = 0; i < 4; i++)
        #pragma unroll
        for (int j = 0; j < 4; j++) acc[i][j] = fz;

    int srow = t >> 2;
    int slc  = (t & 3) ^ ((t >> 2) & 3);
    int sldso = (t >> 6) * 512;

    #pragma unroll
    for (int j = 0; j < 2; j++) {
        int row = 64*j + srow;
        GLD16(wpbf + (size_t)(mBase + row) * 256 + slc * 8, &As[0][j*2048 + sldso]);
        GLD16(aoT  + (size_t)(nBase + row) * 256 + slc * 8, &Bs[0][j*2048 + sldso]);
    }
    int buf = 0;
    for (int kb = 0; kb < 8; kb++) {
        __syncthreads();
        if (kb < 7) {
            #pragma unroll
            for (int j = 0; j < 2; j++) {
                int row = 64*j + srow;
                GLD16(wpbf + (size_t)(mBase + row) * 256 + (kb+1)*32 + slc * 8, &As[buf^1][j*2048 + sldso]);
                GLD16(aoT  + (size_t)(nBase + row) * 256 + (kb+1)*32 + slc * 8, &Bs[buf^1][j*2048 + sldso]);
            }
        }
        short8 af[4], bfr[4];
        #pragma unroll
        for (int mb = 0; mb < 4; mb++)
            af[mb] = *(short8*)&As[buf][(m0 + mb*16 + l16)*32 + ((quad ^ (l16 & 3)) * 8)];
        #pragma unroll
        for (int nb = 0; nb < 4; nb++)
            bfr[nb] = *(short8*)&Bs[buf][(n0 + nb*16 + l16)*32 + ((quad ^ (l16 & 3)) * 8)];
        #pragma unroll
        for (int mb = 0; mb < 4; mb++)
            #pragma unroll
            for (int nb = 0; nb < 4; nb++)
                acc[mb][nb] = __builtin_amdgcn_mfma_f32_16x16x32_bf16(af[mb], bfr[nb], acc[mb][nb], 0, 0, 0);
        buf ^= 1;
    }
    #pragma unroll
    for (int mb = 0; mb < 4; mb++)
        #pragma unroll
        for (int r = 0; r < 4; r++) {
            int m = mBase + m0 + mb*16 + quad*4 + r;
            float bb = bp[m];
            #pragma unroll
            for (int nb = 0; nb < 4; nb++) {
                int n = nBase + n0 + nb*16 + l16;
                size_t idx = ((size_t)(n >> 12) * 256 + m) * 4096 + (n & 4095);
                out[idx] = acc[mb][nb][r] + bb + x[idx];
            }
        }
}

extern "C" void kernel_launch(void* const* d_in, const int* in_sizes, int n_in,
                              void* d_out, int out_size, void* d_ws, size_t ws_size,
                              hipStream_t stream) {
    const float* x     = (const float*)d_in[0];
    const float* gamma = (const float*)d_in[1];
    const float* beta  = (const float*)d_in[2];
    const float* wq    = (const float*)d_in[3];
    const float* bq    = (const float*)d_in[4];
    const float* wk    = (const float*)d_in[5];
    const float* bk    = (const float*)d_in[6];
    const float* wv    = (const float*)d_in[7];
    const float* bv    = (const float*)d_in[8];
    const float* wp    = (const float*)d_in[9];
    const float* bp    = (const float*)d_in[10];
    float* out = (float*)d_out;

    const size_t SZ = (size_t)NB * NPIX * CCH;
    float* part  = (float*)d_ws;
    float* lsum  = part + 512;
    ushort_t* wpbf = (ushort_t*)(lsum + (size_t)NCHUNK * NB * NPIX);
    ushort_t* slot0 = wpbf + 65536;
    ushort_t* Op3 = slot0;
    u8* qT8 = (u8*)(slot0 + SZ);           // fp8, 4 MB used of 8 MB slot
    u8* kT8 = (u8*)(slot0 + 2*SZ);
    u8* vv8 = (u8*)(slot0 + 3*SZ);
    ushort_t* aoT = slot0 + 4*SZ;          // Op0, combined in-place -> aoT
    ushort_t* xnT = (ushort_t*)d_out;      // [0,8M): xnT, later Op1
    ushort_t* Op1 = (ushort_t*)d_out;
    ushort_t* Op2 = (ushort_t*)d_out + SZ; // [8M,16M): wbf (pre-qkv), later Op2
    ushort_t* wbf = (ushort_t*)d_out + SZ;

    gn1w<<<512, 256, 0, stream>>>(x, wq, wk, wv, wp, part, wbf, wpbf);
    gn_transpose<<<dim3(64, 4, 4), 256, 0, stream>>>(x, part, gamma, beta, xnT);
    qkv3<<<dim3(128, 2, 3), 256, 0, stream>>>(xnT, wbf, bq, bk, bv, qT8, kT8, vv8);
    flash_attn<<<dim3(512), 256, 0, stream>>>(qT8, kT8, vv8, aoT, Op1, Op2, Op3, lsum);
    attn_combine<<<(int)(SZ / 1024), 256, 0, stream>>>(aoT, Op1, Op2, Op3, lsum);
    projk<<<dim3(128, 2), 256, 0, stream>>>(wpbf, aoT, bp, x, out);
}